// Round 1
// 115.767 us; speedup vs baseline: 1.0355x; 1.0355x over previous
//
#include <hip/hip_runtime.h>

typedef unsigned int u32;
typedef unsigned short u16;

#define N_BATCH 8192
#define EMB_DIM 128
#define MARGIN 1.0f
#define CAP 256          // max members per class (mean 128, sd ~11)
#define BIGF 3.3e38f

typedef __attribute__((ext_vector_type(8))) short bf16x8;   // 8 bf16 = 4 VGPRs
typedef __attribute__((ext_vector_type(4))) float f32x4;    // MFMA 16x16 acc

// async global->LDS, 16B per lane; lds dest is wave-uniform base (+lane*16 implicit)
__device__ inline void async_ld16(const void* g, void* l) {
    __builtin_amdgcn_global_load_lds(
        (const __attribute__((address_space(1))) unsigned int*)g,
        (__attribute__((address_space(3))) unsigned int*)l, 16, 0, 0);
}

// ---------------------------------------------------------------------------
// Kernel 1: bf16 cast + row sq-norms + init totals.
// ---------------------------------------------------------------------------
__global__ __launch_bounds__(256) void k_prep(const float* __restrict__ emb,
                                              u16* __restrict__ ebf,
                                              float* __restrict__ sq,
                                              u32* __restrict__ totals) {
    int t = threadIdx.x;
    int g = blockIdx.x * 256 + t;
    int r = blockIdx.x * 8 + (t >> 5);
    int l32 = t & 31;
    float4 x = ((const float4*)emb)[(size_t)r * 32 + l32];
    u32 ux = __float_as_uint(x.x), uy = __float_as_uint(x.y);
    u32 uz = __float_as_uint(x.z), uw = __float_as_uint(x.w);
    ushort4 b;
    b.x = (u16)((ux + 0x7fffu + ((ux >> 16) & 1u)) >> 16);
    b.y = (u16)((uy + 0x7fffu + ((uy >> 16) & 1u)) >> 16);
    b.z = (u16)((uz + 0x7fffu + ((uz >> 16) & 1u)) >> 16);
    b.w = (u16)((uw + 0x7fffu + ((uw >> 16) & 1u)) >> 16);
    ((ushort4*)ebf)[(size_t)r * 32 + l32] = b;

    float v = fmaf(x.x, x.x, fmaf(x.y, x.y, fmaf(x.z, x.z, x.w * x.w)));
    v += __shfl_down(v, 16, 64);   // 32-lane reduce
    v += __shfl_down(v, 8, 64);
    v += __shfl_down(v, 4, 64);
    v += __shfl_down(v, 2, 64);
    v += __shfl_down(v, 1, 64);
    if (l32 == 0) sq[r] = v;
    if (g < 4) totals[g] = 0u;     // sumF, cntF, (unused), ticket
}

// ---------------------------------------------------------------------------
// Kernel 2: fused Gram + masked row/col min.  NO global atomics: block (bx,by)
// plain-stores row-mins to partmin[by][R..] and col-mins to partmin[bx][C..].
// For row i in block-row b: row slots cover kk=b..63, col slots kk=0..b-1 —
// a perfect partition of 64 slots, each written exactly once.
// sq/labels for the tile staged in LDS during the B-DMA window.
// launch_bounds(256,3): <=168 VGPR -> no spill risk (MFMA loop holds ~125 live).
// ---------------------------------------------------------------------------
__global__ __launch_bounds__(256, 3) void k_gram(const u16* __restrict__ ebf,
                                                 const float* __restrict__ sq,
                                                 const int* __restrict__ labels,
                                                 float* __restrict__ partmin) {
    // ---- triangular decode: idx -> (bx, by), by >= bx
    int idx = blockIdx.x;
    float ff = (129.0f - sqrtf(16641.0f - 8.0f * (float)idx)) * 0.5f;
    int bx = (int)ff;
    if (bx > 63) bx = 63;
    while (bx > 0 && idx < bx * 64 - (bx * (bx - 1)) / 2) --bx;
    while (idx >= (bx + 1) * 64 - ((bx + 1) * bx) / 2) ++bx;
    int by = bx + idx - (bx * 64 - (bx * (bx - 1)) / 2);
    const int R = bx * 128, C = by * 128;
    const bool diag = (bx == by);

    __shared__ uint4 Bs[2048];            // 32 KB B tile (XOR swizzled via source)
    __shared__ float s_sqR[128], s_sqC[128];
    __shared__ int s_lbR[128], s_lbC[128];
    __shared__ float rowpart[2][128];     // cross-wave combine, plain stores
    __shared__ float colpart[2][128];

    const int t = threadIdx.x;
    const int lane = t & 63, w = t >> 6;
    const int c16 = lane & 15, quad = lane >> 4;
    const uint4* gE = (const uint4*)ebf;

    // stage B tile (rows C..C+127) via async DMA, swizzle folded into source addr
#pragma unroll
    for (int it = 0; it < 8; ++it) {
        int s = w * 512 + it * 64 + lane;
        int row = s >> 4, chPos = s & 15;
        int ch = chPos ^ (row & 15);
        async_ld16(gE + (size_t)(C + row) * 16 + ch, Bs + (w * 512 + it * 64));
    }
    // stage tile sq/labels (removes L2-latency stalls from the epilogue)
    if (t < 128) {
        s_sqR[t] = sq[R + t];
        s_lbR[t] = labels[R + t];
    } else {
        int t2 = t - 128;
        s_sqC[t2] = sq[C + t2];
        s_lbC[t2] = labels[C + t2];
    }

    const int mb = (w & 1) * 64;
    const int nb = (w >> 1) * 64;
    f32x4 acc[4][4];
#pragma unroll
    for (int i = 0; i < 4; ++i)
#pragma unroll
        for (int j = 0; j < 4; ++j) acc[i][j] = (f32x4){0.f, 0.f, 0.f, 0.f};

    const bf16x8* gA8 = (const bf16x8*)ebf;
    bf16x8 a[4];
#pragma unroll
    for (int i = 0; i < 4; ++i)
        a[i] = gA8[(size_t)(R + mb + i * 16 + c16) * 16 + quad];

    __syncthreads();   // drains LDS-DMA + sq/label stages

    const bf16x8* Bs8 = (const bf16x8*)Bs;
#pragma unroll
    for (int kc = 0; kc < 4; ++kc) {
        int kch = kc * 4 + quad;
        bf16x8 b[4];
#pragma unroll
        for (int j = 0; j < 4; ++j) {
            int br = nb + j * 16 + c16;
            b[j] = Bs8[br * 16 + (kch ^ (br & 15))];
        }
        bf16x8 an[4];
        if (kc < 3) {
            int kn = (kc + 1) * 4 + quad;
#pragma unroll
            for (int i = 0; i < 4; ++i)
                an[i] = gA8[(size_t)(R + mb + i * 16 + c16) * 16 + kn];
        }
#pragma unroll
        for (int i = 0; i < 4; ++i)
#pragma unroll
            for (int j = 0; j < 4; ++j)
                acc[i][j] = __builtin_amdgcn_mfma_f32_16x16x32_bf16(a[i], b[j], acc[i][j], 0, 0, 0);
        if (kc < 3) {
#pragma unroll
            for (int i = 0; i < 4; ++i) a[i] = an[i];
        }
    }

    // ---- epilogue: per-wave masked mins (no clamp needed: plain float stores)
    float cs_[4]; int cl_[4];
#pragma unroll
    for (int j = 0; j < 4; ++j) {
        int cc = nb + j * 16 + c16;
        cs_[j] = s_sqC[cc];
        cl_[j] = s_lbC[cc];
    }
    float cm[4] = {BIGF, BIGF, BIGF, BIGF};

#pragma unroll
    for (int i = 0; i < 4; ++i) {
        const int rowbase = mb + i * 16 + quad * 4;
        float rs_[4]; int rl_[4];
#pragma unroll
        for (int rg = 0; rg < 4; ++rg) {
            rs_[rg] = s_sqR[rowbase + rg];
            rl_[rg] = s_lbR[rowbase + rg];
        }
        float rm[4] = {BIGF, BIGF, BIGF, BIGF};
#pragma unroll
        for (int j = 0; j < 4; ++j) {
#pragma unroll
            for (int rg = 0; rg < 4; ++rg) {
                // C/D layout (m89/m91): D[row=quad*4+rg][col=lane&15]
                float d = fmaf(-2.f, acc[i][j][rg], rs_[rg] + cs_[j]);
                bool same = (rl_[rg] == cl_[j]);
                float cand = same ? BIGF : d;
                rm[rg] = fminf(rm[rg], cand);
                cm[j] = fminf(cm[j], cand);
            }
        }
#pragma unroll
        for (int rg = 0; rg < 4; ++rg) {
            float v = rm[rg];
            v = fminf(v, __shfl_xor(v, 1, 64));
            v = fminf(v, __shfl_xor(v, 2, 64));
            v = fminf(v, __shfl_xor(v, 4, 64));
            v = fminf(v, __shfl_xor(v, 8, 64));
            if (c16 == 0) rowpart[w >> 1][rowbase + rg] = v;  // plain store, disjoint slots
        }
    }
    if (!diag) {
#pragma unroll
        for (int j = 0; j < 4; ++j) {
            float v = cm[j];
            v = fminf(v, __shfl_xor(v, 16, 64));
            v = fminf(v, __shfl_xor(v, 32, 64));
            if (quad == 0) colpart[w & 1][nb + j * 16 + c16] = v;
        }
    }
    __syncthreads();

    if (t < 128) {
        float v = fminf(rowpart[0][t], rowpart[1][t]);
        partmin[(size_t)by * N_BATCH + R + t] = v;
    } else if (!diag) {
        int cc = t - 128;
        float v = fminf(colpart[0][cc], colpart[1][cc]);
        partmin[(size_t)bx * N_BATCH + C + cc] = v;
    }
}

// ---------------------------------------------------------------------------
// Kernel 3: fold 64 partials per row into negmin. Coalesced (consecutive i),
// 2 MB total. No atomics anywhere.
// ---------------------------------------------------------------------------
__global__ __launch_bounds__(256) void k_reduce(const float* __restrict__ partmin,
                                                float* __restrict__ negmin) {
    int i = blockIdx.x * 256 + threadIdx.x;
    float v = partmin[i];
#pragma unroll
    for (int kk = 1; kk < 64; ++kk)
        v = fminf(v, partmin[(size_t)kk * N_BATCH + i]);
    negmin[i] = v;
}

// ---------------------------------------------------------------------------
// Kernel 4: per-class pair losses, bounded by actual class size n.
// ---------------------------------------------------------------------------
__global__ __launch_bounds__(256) void k_class(const u16* __restrict__ ebf,
                                               const float* __restrict__ sq,
                                               const int* __restrict__ labels,
                                               const float* __restrict__ negmin,
                                               float* __restrict__ totalsF,
                                               u32* __restrict__ totalsU,
                                               float* __restrict__ out) {
    const int c = blockIdx.x;
    __shared__ uint4 Es[4096];      // 64 KB: up to 256 member rows, XOR-swizzled
    __shared__ u32 lmem[CAP];
    __shared__ float lnm[CAP], lsq[CAP];
    __shared__ u32 lcount;
    __shared__ float redS[4], redC[4];

    const int t = threadIdx.x;
    const int lane = t & 63, w = t >> 6;
    const int c16 = lane & 15, quad = lane >> 4;

    if (t == 0) lcount = 0;
    __syncthreads();
    for (int r = t; r < N_BATCH; r += 256)
        if (labels[r] == c) {
            u32 p = atomicAdd(&lcount, 1u);
            if (p < CAP) lmem[p] = (u32)r;
        }
    __syncthreads();
    int n = lcount; if (n > CAP) n = CAP;
    const int npan = (n + 63) >> 6;          // 64-col panels actually needed

    const uint4* gE = (const uint4*)ebf;
    // gather only the n live rows (pad rows left as garbage; guarded below)
    for (int s = t; s < n * 16; s += 256) {
        int row = s >> 4, ch = s & 15;
        Es[row * 16 + (ch ^ (row & 15))] = gE[(size_t)lmem[row] * 16 + ch];
    }
    if (t < n) { lnm[t] = negmin[lmem[t]]; lsq[t] = sq[lmem[t]]; }
    __syncthreads();

    const bf16x8* Es8 = (const bf16x8*)Es;
    float ssum = 0.f, scnt = 0.f;

    if (w * 64 < n) {                        // whole-wave row bound
        for (int cp = 0; cp < npan; ++cp) {  // col panels of 64
            f32x4 acc[4][4];
#pragma unroll
            for (int i = 0; i < 4; ++i)
#pragma unroll
                for (int j = 0; j < 4; ++j) acc[i][j] = (f32x4){0.f, 0.f, 0.f, 0.f};
#pragma unroll
            for (int kc = 0; kc < 4; ++kc) {
                int kch = kc * 4 + quad;
                bf16x8 a[4], b[4];
#pragma unroll
                for (int i = 0; i < 4; ++i) {
                    int ar = w * 64 + i * 16 + c16;
                    a[i] = Es8[ar * 16 + (kch ^ (ar & 15))];
                }
#pragma unroll
                for (int j = 0; j < 4; ++j) {
                    int br = cp * 64 + j * 16 + c16;
                    b[j] = Es8[br * 16 + (kch ^ (br & 15))];
                }
#pragma unroll
                for (int i = 0; i < 4; ++i) {
                    if (w * 64 + i * 16 >= n) continue;   // dead row-group
#pragma unroll
                    for (int j = 0; j < 4; ++j)
                        acc[i][j] = __builtin_amdgcn_mfma_f32_16x16x32_bf16(a[i], b[j], acc[i][j], 0, 0, 0);
                }
            }
            // epilogue for this 64x64 sub-tile
            float lsqq[4]; u32 oq[4]; bool qv[4];
#pragma unroll
            for (int j = 0; j < 4; ++j) {
                int q = cp * 64 + j * 16 + c16;
                qv[j] = (q < n);
                lsqq[j] = qv[j] ? lsq[q] : 0.f;
                oq[j] = qv[j] ? lmem[q] : 0u;            // 0 sentinel: opp<0 never true
            }
#pragma unroll
            for (int i = 0; i < 4; ++i) {
                if (w * 64 + i * 16 >= n) continue;
                int pb = w * 64 + i * 16 + quad * 4;
                float rcst[4]; u32 opp[4];
#pragma unroll
                for (int rg = 0; rg < 4; ++rg) {
                    int p = pb + rg;
                    bool pv = (p < n);
                    rcst[rg] = pv ? (lsq[p] - lnm[p] + MARGIN) : -BIGF;
                    opp[rg] = pv ? lmem[p] : 0xffffffffu; // max sentinel: opp<oq never true
                }
#pragma unroll
                for (int j = 0; j < 4; ++j)
#pragma unroll
                    for (int rg = 0; rg < 4; ++rg) {
                        float val = fmaf(-2.f, acc[i][j][rg], rcst[rg] + lsqq[j]);
                        bool ok = qv[j] && (opp[rg] < oq[j]) && (val > 0.f);
                        if (ok) { ssum += val; scnt += 1.f; }
                    }
            }
        }
    }

#pragma unroll
    for (int off = 32; off > 0; off >>= 1) {
        ssum += __shfl_down(ssum, off, 64);
        scnt += __shfl_down(scnt, off, 64);
    }
    if (lane == 0) { redS[w] = ssum; redC[w] = scnt; }
    __syncthreads();
    if (t == 0) {
        float S = redS[0] + redS[1] + redS[2] + redS[3];
        float Cc = redC[0] + redC[1] + redC[2] + redC[3];
        atomicAdd(&totalsF[0], S);
        atomicAdd(&totalsF[1], Cc);
        __threadfence();
        u32 tk = atomicAdd(&totalsU[3], 1u);
        if (tk == 63u) {                 // last class block: finalize
            __threadfence();
            float fs = atomicAdd(&totalsF[0], 0.f);
            float fc = atomicAdd(&totalsF[1], 0.f);
            out[0] = fs / fmaxf(fc, 1.0f);
        }
    }
}

// ---------------------------------------------------------------------------
extern "C" void kernel_launch(void* const* d_in, const int* in_sizes, int n_in,
                              void* d_out, int out_size, void* d_ws, size_t ws_size,
                              hipStream_t stream) {
    const float* emb = (const float*)d_in[0];
    const int* labels = (const int*)d_in[1];

    char* w = (char*)d_ws;
    const size_t ebf_bytes = (size_t)N_BATCH * EMB_DIM * sizeof(u16);   // 2 MB
    u16* ebf = (u16*)w;
    size_t off = ebf_bytes;
    float* sq = (float*)(w + off);      off += (size_t)N_BATCH * 4;     // 32 KB
    float* partmin = (float*)(w + off); off += (size_t)64 * N_BATCH * 4;// 2 MB
    float* negmin = (float*)(w + off);  off += (size_t)N_BATCH * 4;     // 32 KB
    u32* totals = (u32*)(w + off);      off += 256;

    k_prep<<<N_BATCH / 8, 256, 0, stream>>>(emb, ebf, sq, totals);
    k_gram<<<2080, 256, 0, stream>>>(ebf, sq, labels, partmin);
    k_reduce<<<N_BATCH / 256, 256, 0, stream>>>(partmin, negmin);
    k_class<<<64, 256, 0, stream>>>(ebf, sq, labels, negmin,
                                    (float*)totals, totals, (float*)d_out);
}